// Round 3
// baseline (538.925 us; speedup 1.0000x reference)
//
#include <hip/hip_runtime.h>

typedef unsigned short u16;
typedef unsigned int   u32;
typedef __attribute__((ext_vector_type(4))) float f32x4;
typedef __attribute__((ext_vector_type(4))) u32   u32x4;
typedef __attribute__((ext_vector_type(8))) __bf16 bf16x8;

constexpr int NV   = 50000;   // vertices
constexpr int NE   = 25000;   // hyperedges
constexpr int NNZp = 400000;  // incidence pairs
constexpr int D    = 512;     // d_in == d_out
constexpr int MP   = 50048;   // NV padded to 128 (391*128)
constexpr int NBE  = 25;      // scan blocks for E (1024 elems each)
constexpr int NBV  = 49;      // scan blocks for V

static __device__ __forceinline__ u16 f2bf(float f) {
  u32 u = __float_as_uint(f);
  u32 r = (u + 0x7fffu + ((u >> 16) & 1u)) >> 16;  // RNE
  return (u16)r;
}
static __device__ __forceinline__ u32 pk2(float a, float b) {
  return (u32)f2bf(a) | ((u32)f2bf(b) << 16);
}

static __device__ __forceinline__ void gload_lds16(const u16* g, u16* l) {
  // async global->LDS, 16B per lane; LDS dest = wave-uniform base + lane*16
  __builtin_amdgcn_global_load_lds(
      (const __attribute__((address_space(1))) u32*)g,
      (__attribute__((address_space(3))) u32*)l, 16, 0, 0);
}

// ---------------- zero segment counters ----------------
__global__ void zero_kernel(int* cntE, int* cntV) {
  int i = blockIdx.x * 256 + threadIdx.x;
  if (i < NE) cntE[i] = 0;
  if (i < NV) cntV[i] = 0;
}

// ---------------- histogram of incidence pairs ----------------
__global__ void hist_kernel(const int* __restrict__ vidx, const int* __restrict__ eidx,
                            int* cntE, int* cntV) {
  int i = blockIdx.x * 256 + threadIdx.x;
  if (i < NNZp) {
    atomicAdd(&cntE[eidx[i]], 1);
    atomicAdd(&cntV[vidx[i]], 1);
  }
}

// ---------------- scan pass 1: per-block (1024 elems) local exclusive scan -----------
__global__ __launch_bounds__(256) void scan1_kernel(
    const int* __restrict__ cntE, const int* __restrict__ cntV,
    int* offE, int* offV, int* blkSum) {
  const bool isE = blockIdx.x < NBE;
  const int* cnt = isE ? cntE : cntV;
  int* off = isE ? offE : offV;
  const int len = isE ? NE : NV;
  const int t = threadIdx.x;
  const int base = (isE ? blockIdx.x : blockIdx.x - NBE) * 1024 + t * 4;
  int4 c = {0, 0, 0, 0};
  if (base + 4 <= len) c = *(const int4*)(cnt + base);
  else {
    if (base + 0 < len) c.x = cnt[base + 0];
    if (base + 1 < len) c.y = cnt[base + 1];
    if (base + 2 < len) c.z = cnt[base + 2];
    if (base + 3 < len) c.w = cnt[base + 3];
  }
  int s = c.x + c.y + c.z + c.w;
  __shared__ int sm[256];
  sm[t] = s;
  __syncthreads();
  for (int d = 1; d < 256; d <<= 1) {
    int u = (t >= d) ? sm[t - d] : 0;
    __syncthreads();
    sm[t] += u;
    __syncthreads();
  }
  int ex = sm[t] - s;  // exclusive prefix within block
  int4 o;
  o.x = ex; o.y = o.x + c.x; o.z = o.y + c.y; o.w = o.z + c.z;
  if (base + 4 <= len) *(int4*)(off + base) = o;
  else {
    if (base + 0 < len) off[base + 0] = o.x;
    if (base + 1 < len) off[base + 1] = o.y;
    if (base + 2 < len) off[base + 2] = o.z;
    if (base + 3 < len) off[base + 3] = o.w;
  }
  if (t == 255) blkSum[blockIdx.x] = sm[255];
}

// ---------------- scan pass 2: wave-scan the 25+49 block sums (in-place, exclusive) --
__global__ void scan2_kernel(int* blkSum) {
  int wv = threadIdx.x >> 6, lane = threadIdx.x & 63;
  int off = wv ? NBE : 0, len = wv ? NBV : NBE;
  int v = (lane < len) ? blkSum[off + lane] : 0;
  int incl = v;
#pragma unroll
  for (int d = 1; d < 64; d <<= 1) {
    int u = __shfl_up(incl, d, 64);
    if (lane >= d) incl += u;
  }
  if (lane < len) blkSum[off + lane] = incl - v;
}

// ---------------- scan pass 3: add block prefixes, materialize off & cur -------------
__global__ __launch_bounds__(256) void scan3_kernel(
    int* offE, int* offV, int* curE, int* curV, const int* __restrict__ blkSum) {
  const bool isE = blockIdx.x < NBE;
  int* off = isE ? offE : offV;
  int* cur = isE ? curE : curV;
  const int len = isE ? NE : NV;
  const int pref = blkSum[blockIdx.x];
  const int base = (isE ? blockIdx.x : blockIdx.x - NBE) * 1024 + threadIdx.x * 4;
  if (base + 4 <= len) {
    int4 o = *(int4*)(off + base);
    o.x += pref; o.y += pref; o.z += pref; o.w += pref;
    *(int4*)(off + base) = o;
    *(int4*)(cur + base) = o;
  } else {
    for (int q = 0; q < 4; q++)
      if (base + q < len) { int v = off[base + q] + pref; off[base + q] = v; cur[base + q] = v; }
  }
}

// ---------------- scatter pairs into CSR ----------------
__global__ void scatter_kernel(const int* __restrict__ vidx, const int* __restrict__ eidx,
                               int* curE, int* curV, int* csr_ev, int* csr_ve) {
  int i = blockIdx.x * 256 + threadIdx.x;
  if (i < NNZp) {
    int e = eidx[i], v = vidx[i];
    csr_ev[atomicAdd(&curE[e], 1)] = v;  // edge -> member vertices
    csr_ve[atomicAdd(&curV[v], 1)] = e;  // vertex -> incident edges
  }
}

// ---------------- fp32 -> bf16 convert (X then W, one grid) --------------------------
__global__ __launch_bounds__(256) void convert_kernel(
    const float* __restrict__ X, const float* __restrict__ W,
    u16* __restrict__ Xb, u16* __restrict__ Wb) {
  constexpr size_t NX = (size_t)NV * D;  // 25,600,000 (divisible by 8)
  size_t i = ((size_t)blockIdx.x * 256 + threadIdx.x) * 8;
  const float* src;
  u16* dst;
  if (i < NX) { src = X + i; dst = Xb + i; }
  else        { src = W + (i - NX); dst = Wb + (i - NX); }  // grid sized exactly
  f32x4 a = *(const f32x4*)src;
  f32x4 b = *(const f32x4*)(src + 4);
  u32x4 p = { pk2(a[0], a[1]), pk2(a[2], a[3]), pk2(b[0], b[1]), pk2(b[2], b[3]) };
  *(u32x4*)dst = p;
}

// ---------------- GEMM: Xp = Xb @ Wb^T, bf16 MFMA, global_load_lds staging -----------
// 128x128 tile, BK=32, 4 waves of 64x64, 16x16x32 MFMA (m97 structure).
__global__ __launch_bounds__(256) void gemm_kernel(const u16* __restrict__ A,
                                                   const u16* __restrict__ B,
                                                   u16* __restrict__ C) {
  __shared__ u16 sA[128 * 32];
  __shared__ u16 sB[128 * 32];
  const int tid  = threadIdx.x;
  const int lane = tid & 63;
  const int wave = tid >> 6;
  const int bm = blockIdx.y * 128;
  const int bn = blockIdx.x * 128;
  const int wm = (wave >> 1) * 64;
  const int wn = (wave & 1) * 64;
  const int lr = lane & 15;
  const int lk = (lane >> 4) * 8;
  const int srow = lane >> 2;        // 0..15: row within 16-row staging stripe
  const int scol = (lane & 3) * 8;   // 0/8/16/24: k-elem offset (16B)

  f32x4 acc[4][4] = {};

  for (int kt = 0; kt < D; kt += 32) {
    __syncthreads();  // previous iteration's LDS readers done
#pragma unroll
    for (int c = 0; c < 2; c++) {
      const int ar = wave * 16 + c * 64;          // wave-uniform stripe base row
      gload_lds16(A + (size_t)(bm + ar + srow) * D + kt + scol, &sA[ar * 32]);
      gload_lds16(B + (size_t)(bn + ar + srow) * D + kt + scol, &sB[ar * 32]);
    }
    __syncthreads();  // drains vmcnt: staging complete

    bf16x8 af[4], bfr[4];
#pragma unroll
    for (int i = 0; i < 4; i++) af[i]  = *(const bf16x8*)&sA[(wm + i * 16 + lr) * 32 + lk];
#pragma unroll
    for (int j = 0; j < 4; j++) bfr[j] = *(const bf16x8*)&sB[(wn + j * 16 + lr) * 32 + lk];
#pragma unroll
    for (int i = 0; i < 4; i++)
#pragma unroll
      for (int j = 0; j < 4; j++)
        acc[i][j] = __builtin_amdgcn_mfma_f32_16x16x32_bf16(af[i], bfr[j], acc[i][j], 0, 0, 0);
  }

  // C/D layout (16x16): col = lane&15, row = (lane>>4)*4 + reg
#pragma unroll
  for (int i = 0; i < 4; i++)
#pragma unroll
    for (int r = 0; r < 4; r++) {
      int row = bm + wm + i * 16 + (lane >> 4) * 4 + r;
      u16* crow = C + (size_t)row * D + bn + wn + lr;
#pragma unroll
      for (int j = 0; j < 4; j++) crow[j * 16] = f2bf(acc[i][j][r]);
    }
}

// ---------------- stage 1: vertex -> hyperedge, column-sliced gather -----------------
// slice = blockIdx & 7 -> 64 columns; with round-robin XCD dispatch each XCD gathers
// only its 64-col slice of Xp (6.4 MB footprint). Wave = 8 groups x 8 lanes; group g
// gathers row idx[base+g]'s 128B slice; cross-group shfl_xor reduce at the end.
__global__ __launch_bounds__(256) void stage1_kernel(
    const u16* __restrict__ Xp, const int* __restrict__ offE, const int* __restrict__ cntE,
    const int* __restrict__ csr_ev, const float* __restrict__ degE,
    const float* __restrict__ Wdiag, u16* __restrict__ Xe) {
  const int wave  = threadIdx.x >> 6;
  const int lane  = threadIdx.x & 63;
  const int g     = lane >> 3;      // 0..7 gather group
  const int c     = lane & 7;       // 0..7 within group (8 bf16 = 16B each)
  const int slice = blockIdx.x & 7;
  const int e     = (blockIdx.x >> 3) * 4 + wave;   // NE % 4 == 0
  const int start = offE[e], cnt = cntE[e];
  const int col0  = slice * 64 + c * 8;
  float acc[8] = {};
  for (int base = 0; base < cnt; base += 8) {
    int j = base + g;
    if (j < cnt) {
      int v = csr_ev[start + j];
      u32x4 p = *(const u32x4*)(Xp + (size_t)v * D + col0);
#pragma unroll
      for (int q = 0; q < 4; q++) {
        u32 u = p[q];
        acc[2 * q]     += __uint_as_float(u << 16);
        acc[2 * q + 1] += __uint_as_float(u & 0xffff0000u);
      }
    }
  }
#pragma unroll
  for (int q = 0; q < 8; q++) {
    float s = acc[q];
    s += __shfl_xor(s, 8, 64);
    s += __shfl_xor(s, 16, 64);
    s += __shfl_xor(s, 32, 64);
    acc[q] = s;
  }
  if (g == 0) {
    float s = degE[e] * Wdiag[e];
    u32x4 o = { pk2(acc[0] * s, acc[1] * s), pk2(acc[2] * s, acc[3] * s),
                pk2(acc[4] * s, acc[5] * s), pk2(acc[6] * s, acc[7] * s) };
    *(u32x4*)(Xe + (size_t)e * D + col0) = o;   // 8 lanes x 16B = 128B contiguous
  }
}

// ---------------- stage 2: hyperedge -> vertex, column-sliced gather -----------------
// Xe slice footprint = 3.2 MB per XCD -> fits 4 MB L2: gathers are L2-hits after warm.
__global__ __launch_bounds__(256) void stage2_kernel(
    const u16* __restrict__ Xe, const int* __restrict__ offV, const int* __restrict__ cntV,
    const int* __restrict__ csr_ve, const float* __restrict__ degV, float* __restrict__ out) {
  const int wave  = threadIdx.x >> 6;
  const int lane  = threadIdx.x & 63;
  const int g     = lane >> 3;
  const int c     = lane & 7;
  const int slice = blockIdx.x & 7;
  const int v     = (blockIdx.x >> 3) * 4 + wave;   // NV % 4 == 0
  const int start = offV[v], cnt = cntV[v];
  const int col0  = slice * 64 + c * 8;
  float acc[8] = {};
  for (int base = 0; base < cnt; base += 8) {
    int j = base + g;
    if (j < cnt) {
      int e = csr_ve[start + j];
      u32x4 p = *(const u32x4*)(Xe + (size_t)e * D + col0);
#pragma unroll
      for (int q = 0; q < 4; q++) {
        u32 u = p[q];
        acc[2 * q]     += __uint_as_float(u << 16);
        acc[2 * q + 1] += __uint_as_float(u & 0xffff0000u);
      }
    }
  }
#pragma unroll
  for (int q = 0; q < 8; q++) {
    float s = acc[q];
    s += __shfl_xor(s, 8, 64);
    s += __shfl_xor(s, 16, 64);
    s += __shfl_xor(s, 32, 64);
    acc[q] = s;
  }
  if (g == 0) {
    float s = degV[v];
    float* orow = out + (size_t)v * D + col0;
    f32x4 o0 = { acc[0] * s, acc[1] * s, acc[2] * s, acc[3] * s };
    f32x4 o1 = { acc[4] * s, acc[5] * s, acc[6] * s, acc[7] * s };
    *(f32x4*)orow = o0;                 // 8 lanes x 32B = 256B contiguous
    *(f32x4*)(orow + 4) = o1;
  }
}

extern "C" void kernel_launch(void* const* d_in, const int* in_sizes, int n_in,
                              void* d_out, int out_size, void* d_ws, size_t ws_size,
                              hipStream_t stream) {
  const float* X     = (const float*)d_in[0];
  const float* W     = (const float*)d_in[1];
  const float* degE  = (const float*)d_in[2];
  const float* degV  = (const float*)d_in[3];
  const float* Wdiag = (const float*)d_in[4];
  const int*   vidx  = (const int*)d_in[5];
  const int*   eidx  = (const int*)d_in[6];
  float* out = (float*)d_out;

  // workspace carve (all 256B aligned); total ~82 MB
  char* p = (char*)d_ws;
  auto take = [&](size_t bytes) { char* r = p; p += (bytes + 255) & ~(size_t)255; return r; };
  u16* Xb     = (u16*)take((size_t)MP * D * 2);   // bf16 X (rows >= NV unused garbage)
  u16* Wb     = (u16*)take((size_t)D * D * 2);    // bf16 W
  u16* Xp     = (u16*)take((size_t)MP * D * 2);   // bf16 projected features
  u16* Xe     = (u16*)take((size_t)NE * D * 2);   // bf16 edge features
  int* cntE   = (int*)take((size_t)NE * 4);
  int* offE   = (int*)take((size_t)NE * 4);
  int* curE   = (int*)take((size_t)NE * 4);
  int* cntV   = (int*)take((size_t)NV * 4);
  int* offV   = (int*)take((size_t)NV * 4);
  int* curV   = (int*)take((size_t)NV * 4);
  int* csr_ev = (int*)take((size_t)NNZp * 4);
  int* csr_ve = (int*)take((size_t)NNZp * 4);
  int* blkSum = (int*)take((size_t)(NBE + NBV) * 4);

  constexpr size_t NCONV = ((size_t)NV * D + (size_t)D * D) / 8 / 256;  // 12628 exact

  zero_kernel   <<<(NV + 255) / 256, 256, 0, stream>>>(cntE, cntV);
  hist_kernel   <<<(NNZp + 255) / 256, 256, 0, stream>>>(vidx, eidx, cntE, cntV);
  scan1_kernel  <<<NBE + NBV, 256, 0, stream>>>(cntE, cntV, offE, offV, blkSum);
  scan2_kernel  <<<1, 128, 0, stream>>>(blkSum);
  scan3_kernel  <<<NBE + NBV, 256, 0, stream>>>(offE, offV, curE, curV, blkSum);
  scatter_kernel<<<(NNZp + 255) / 256, 256, 0, stream>>>(vidx, eidx, curE, curV, csr_ev, csr_ve);
  convert_kernel<<<NCONV, 256, 0, stream>>>(X, W, Xb, Wb);
  gemm_kernel   <<<dim3(D / 128, MP / 128), 256, 0, stream>>>(Xb, Wb, Xp);
  stage1_kernel <<<(NE / 4) * 8, 256, 0, stream>>>(Xp, offE, cntE, csr_ev, degE, Wdiag, Xe);
  stage2_kernel <<<(NV / 4) * 8, 256, 0, stream>>>(Xe, offV, cntV, csr_ve, degV, out);
}

// Round 4
// 459.721 us; speedup vs baseline: 1.1723x; 1.1723x over previous
//
#include <hip/hip_runtime.h>

typedef unsigned short u16;
typedef unsigned int   u32;
typedef __attribute__((ext_vector_type(4))) float f32x4;
typedef __attribute__((ext_vector_type(4))) u32   u32x4;
typedef __attribute__((ext_vector_type(8))) __bf16 bf16x8;

constexpr int NV   = 50000;   // vertices
constexpr int NE   = 25000;   // hyperedges
constexpr int NNZp = 400000;  // incidence pairs
constexpr int D    = 512;     // d_in == d_out
constexpr int MP   = 50048;   // NV padded to 128 (391*128)
constexpr int NBE  = 25;      // scan blocks for E (1024 elems each)
constexpr int NBV  = 49;      // scan blocks for V
constexpr int SG1  = 391;     // stage1 segment-groups: ceil(NE/64)
constexpr int SG2  = 1563;    // stage2 segment-groups: ceil(NV/32)

static __device__ __forceinline__ u16 f2bf(float f) {
  u32 u = __float_as_uint(f);
  u32 r = (u + 0x7fffu + ((u >> 16) & 1u)) >> 16;  // RNE
  return (u16)r;
}
static __device__ __forceinline__ u32 pk2(float a, float b) {
  return (u32)f2bf(a) | ((u32)f2bf(b) << 16);
}

static __device__ __forceinline__ void gload_lds16(const u16* g, u16* l) {
  // async global->LDS, 16B per lane; LDS dest = wave-uniform base + lane*16
  __builtin_amdgcn_global_load_lds(
      (const __attribute__((address_space(1))) u32*)g,
      (__attribute__((address_space(3))) u32*)l, 16, 0, 0);
}

// ---------------- zero segment counters ----------------
__global__ void zero_kernel(int* cntE, int* cntV) {
  int i = blockIdx.x * 256 + threadIdx.x;
  if (i < NE) cntE[i] = 0;
  if (i < NV) cntV[i] = 0;
}

// ---------------- histogram of incidence pairs ----------------
__global__ void hist_kernel(const int* __restrict__ vidx, const int* __restrict__ eidx,
                            int* cntE, int* cntV) {
  int i = blockIdx.x * 256 + threadIdx.x;
  if (i < NNZp) {
    atomicAdd(&cntE[eidx[i]], 1);
    atomicAdd(&cntV[vidx[i]], 1);
  }
}

// ---------------- scan pass 1: per-block (1024 elems) local exclusive scan -----------
__global__ __launch_bounds__(256) void scan1_kernel(
    const int* __restrict__ cntE, const int* __restrict__ cntV,
    int* offE, int* offV, int* blkSum) {
  const bool isE = blockIdx.x < NBE;
  const int* cnt = isE ? cntE : cntV;
  int* off = isE ? offE : offV;
  const int len = isE ? NE : NV;
  const int t = threadIdx.x;
  const int base = (isE ? blockIdx.x : blockIdx.x - NBE) * 1024 + t * 4;
  int4 c = {0, 0, 0, 0};
  if (base + 4 <= len) c = *(const int4*)(cnt + base);
  else {
    if (base + 0 < len) c.x = cnt[base + 0];
    if (base + 1 < len) c.y = cnt[base + 1];
    if (base + 2 < len) c.z = cnt[base + 2];
    if (base + 3 < len) c.w = cnt[base + 3];
  }
  int s = c.x + c.y + c.z + c.w;
  __shared__ int sm[256];
  sm[t] = s;
  __syncthreads();
  for (int d = 1; d < 256; d <<= 1) {
    int u = (t >= d) ? sm[t - d] : 0;
    __syncthreads();
    sm[t] += u;
    __syncthreads();
  }
  int ex = sm[t] - s;  // exclusive prefix within block
  int4 o;
  o.x = ex; o.y = o.x + c.x; o.z = o.y + c.y; o.w = o.z + c.z;
  if (base + 4 <= len) *(int4*)(off + base) = o;
  else {
    if (base + 0 < len) off[base + 0] = o.x;
    if (base + 1 < len) off[base + 1] = o.y;
    if (base + 2 < len) off[base + 2] = o.z;
    if (base + 3 < len) off[base + 3] = o.w;
  }
  if (t == 255) blkSum[blockIdx.x] = sm[255];
}

// ---------------- scan pass 2: wave-scan the 25+49 block sums (in-place, exclusive) --
__global__ void scan2_kernel(int* blkSum) {
  int wv = threadIdx.x >> 6, lane = threadIdx.x & 63;
  int off = wv ? NBE : 0, len = wv ? NBV : NBE;
  int v = (lane < len) ? blkSum[off + lane] : 0;
  int incl = v;
#pragma unroll
  for (int d = 1; d < 64; d <<= 1) {
    int u = __shfl_up(incl, d, 64);
    if (lane >= d) incl += u;
  }
  if (lane < len) blkSum[off + lane] = incl - v;
}

// ---------------- scan pass 3: add block prefixes, materialize off & cur -------------
__global__ __launch_bounds__(256) void scan3_kernel(
    int* offE, int* offV, int* curE, int* curV, const int* __restrict__ blkSum) {
  const bool isE = blockIdx.x < NBE;
  int* off = isE ? offE : offV;
  int* cur = isE ? curE : curV;
  const int len = isE ? NE : NV;
  const int pref = blkSum[blockIdx.x];
  const int base = (isE ? blockIdx.x : blockIdx.x - NBE) * 1024 + threadIdx.x * 4;
  if (base + 4 <= len) {
    int4 o = *(int4*)(off + base);
    o.x += pref; o.y += pref; o.z += pref; o.w += pref;
    *(int4*)(off + base) = o;
    *(int4*)(cur + base) = o;
  } else {
    for (int q = 0; q < 4; q++)
      if (base + q < len) { int v = off[base + q] + pref; off[base + q] = v; cur[base + q] = v; }
  }
}

// ---------------- scatter pairs into CSR ----------------
__global__ void scatter_kernel(const int* __restrict__ vidx, const int* __restrict__ eidx,
                               int* curE, int* curV, int* csr_ev, int* csr_ve) {
  int i = blockIdx.x * 256 + threadIdx.x;
  if (i < NNZp) {
    int e = eidx[i], v = vidx[i];
    csr_ev[atomicAdd(&curE[e], 1)] = v;  // edge -> member vertices
    csr_ve[atomicAdd(&curV[v], 1)] = e;  // vertex -> incident edges
  }
}

// ---------------- fp32 -> bf16 convert (X then W, one grid) --------------------------
__global__ __launch_bounds__(256) void convert_kernel(
    const float* __restrict__ X, const float* __restrict__ W,
    u16* __restrict__ Xb, u16* __restrict__ Wb) {
  constexpr size_t NX = (size_t)NV * D;  // 25,600,000 (divisible by 8)
  size_t i = ((size_t)blockIdx.x * 256 + threadIdx.x) * 8;
  const float* src;
  u16* dst;
  if (i < NX) { src = X + i; dst = Xb + i; }
  else        { src = W + (i - NX); dst = Wb + (i - NX); }  // grid sized exactly
  f32x4 a = *(const f32x4*)src;
  f32x4 b = *(const f32x4*)(src + 4);
  u32x4 p = { pk2(a[0], a[1]), pk2(a[2], a[3]), pk2(b[0], b[1]), pk2(b[2], b[3]) };
  *(u32x4*)dst = p;
}

// ---------------- GEMM: Xp = Xb @ Wb^T, bf16 MFMA, global_load_lds staging -----------
// 128x128 tile, BK=32, 4 waves of 64x64, 16x16x32 MFMA (m97 structure).
__global__ __launch_bounds__(256) void gemm_kernel(const u16* __restrict__ A,
                                                   const u16* __restrict__ B,
                                                   u16* __restrict__ C) {
  __shared__ u16 sA[128 * 32];
  __shared__ u16 sB[128 * 32];
  const int tid  = threadIdx.x;
  const int lane = tid & 63;
  const int wave = tid >> 6;
  const int bm = blockIdx.y * 128;
  const int bn = blockIdx.x * 128;
  const int wm = (wave >> 1) * 64;
  const int wn = (wave & 1) * 64;
  const int lr = lane & 15;
  const int lk = (lane >> 4) * 8;
  const int srow = lane >> 2;        // 0..15: row within 16-row staging stripe
  const int scol = (lane & 3) * 8;   // 0/8/16/24: k-elem offset (16B)

  f32x4 acc[4][4] = {};

  for (int kt = 0; kt < D; kt += 32) {
    __syncthreads();  // previous iteration's LDS readers done
#pragma unroll
    for (int c = 0; c < 2; c++) {
      const int ar = wave * 16 + c * 64;          // wave-uniform stripe base row
      gload_lds16(A + (size_t)(bm + ar + srow) * D + kt + scol, &sA[ar * 32]);
      gload_lds16(B + (size_t)(bn + ar + srow) * D + kt + scol, &sB[ar * 32]);
    }
    __syncthreads();  // drains vmcnt: staging complete

    bf16x8 af[4], bfr[4];
#pragma unroll
    for (int i = 0; i < 4; i++) af[i]  = *(const bf16x8*)&sA[(wm + i * 16 + lr) * 32 + lk];
#pragma unroll
    for (int j = 0; j < 4; j++) bfr[j] = *(const bf16x8*)&sB[(wn + j * 16 + lr) * 32 + lk];
#pragma unroll
    for (int i = 0; i < 4; i++)
#pragma unroll
      for (int j = 0; j < 4; j++)
        acc[i][j] = __builtin_amdgcn_mfma_f32_16x16x32_bf16(af[i], bfr[j], acc[i][j], 0, 0, 0);
  }

  // C/D layout (16x16): col = lane&15, row = (lane>>4)*4 + reg
#pragma unroll
  for (int i = 0; i < 4; i++)
#pragma unroll
    for (int r = 0; r < 4; r++) {
      int row = bm + wm + i * 16 + (lane >> 4) * 4 + r;
      u16* crow = C + (size_t)row * D + bn + wn + lr;
#pragma unroll
      for (int j = 0; j < 4; j++) crow[j * 16] = f2bf(acc[i][j][r]);
    }
}

// ---------------- stage 1: vertex -> hyperedge ---------------------------------------
// 16 column slices of 32 cols; phase-major grid ordering so each XCD works on ONE
// 3.2 MB Xp slice at a time (fits 4 MB L2). Wave = 16 groups x 4 lanes; each group
// owns one edge segment and privately accumulates its 64B row-slice (no cross-group
// reduction). Index prefetch overlaps the idx load with the dependent gather.
__global__ __launch_bounds__(256) void stage1_kernel(
    const u16* __restrict__ Xp, const int* __restrict__ offE, const int* __restrict__ cntE,
    const int* __restrict__ csr_ev, const float* __restrict__ degE,
    const float* __restrict__ Wdiag, u16* __restrict__ Xe) {
  const int wave = threadIdx.x >> 6;
  const int lane = threadIdx.x & 63;
  const int g    = lane >> 2;      // 0..15 group = segment
  const int c    = lane & 3;       // 4 lanes x 16B = 64B = 32 cols
  const int bid  = blockIdx.x;
  const int xcd  = bid & 7;
  const int tmp  = bid >> 3;                    // 0 .. 2*SG1-1
  const int phase = (tmp >= SG1) ? 1 : 0;       // phase-major: all XCDs finish slices
  const int sg    = tmp - phase * SG1;          //  0..7 before starting 8..15
  const int slice = xcd + 8 * phase;
  const int e     = sg * 64 + wave * 16 + g;
  const int col0  = slice * 32 + c * 8;
  int start = 0, cnt = 0;
  if (e < NE) { start = offE[e]; cnt = cntE[e]; }
  float acc[8] = {};
  int nxt = (cnt > 0) ? csr_ev[start] : 0;
  for (int j = 0; j < cnt; j++) {
    int v = nxt;
    if (j + 1 < cnt) nxt = csr_ev[start + j + 1];
    u32x4 p = *(const u32x4*)(Xp + (size_t)v * D + col0);
#pragma unroll
    for (int q = 0; q < 4; q++) {
      u32 u = p[q];
      acc[2 * q]     += __uint_as_float(u << 16);
      acc[2 * q + 1] += __uint_as_float(u & 0xffff0000u);
    }
  }
  if (e < NE) {
    float s = degE[e] * Wdiag[e];
    u32x4 o = { pk2(acc[0] * s, acc[1] * s), pk2(acc[2] * s, acc[3] * s),
                pk2(acc[4] * s, acc[5] * s), pk2(acc[6] * s, acc[7] * s) };
    *(u32x4*)(Xe + (size_t)e * D + col0) = o;
  }
}

// ---------------- stage 2: hyperedge -> vertex ---------------------------------------
// 8 column slices of 64 cols (Xe slice = 3.2 MB per XCD, fits L2). Wave = 8 groups x
// 8 lanes; each group owns one vertex segment, accumulates its 128B slice privately.
__global__ __launch_bounds__(256) void stage2_kernel(
    const u16* __restrict__ Xe, const int* __restrict__ offV, const int* __restrict__ cntV,
    const int* __restrict__ csr_ve, const float* __restrict__ degV, float* __restrict__ out) {
  const int wave = threadIdx.x >> 6;
  const int lane = threadIdx.x & 63;
  const int g    = lane >> 3;      // 0..7 group = segment
  const int c    = lane & 7;       // 8 lanes x 16B = 128B = 64 cols
  const int slice = blockIdx.x & 7;
  const int sg    = blockIdx.x >> 3;
  const int v     = sg * 32 + wave * 8 + g;
  const int col0  = slice * 64 + c * 8;
  int start = 0, cnt = 0;
  if (v < NV) { start = offV[v]; cnt = cntV[v]; }
  float acc[8] = {};
  int nxt = (cnt > 0) ? csr_ve[start] : 0;
  for (int j = 0; j < cnt; j++) {
    int e = nxt;
    if (j + 1 < cnt) nxt = csr_ve[start + j + 1];
    u32x4 p = *(const u32x4*)(Xe + (size_t)e * D + col0);
#pragma unroll
    for (int q = 0; q < 4; q++) {
      u32 u = p[q];
      acc[2 * q]     += __uint_as_float(u << 16);
      acc[2 * q + 1] += __uint_as_float(u & 0xffff0000u);
    }
  }
  if (v < NV) {
    float s = degV[v];
    float* orow = out + (size_t)v * D + col0;
    f32x4 o0 = { acc[0] * s, acc[1] * s, acc[2] * s, acc[3] * s };
    f32x4 o1 = { acc[4] * s, acc[5] * s, acc[6] * s, acc[7] * s };
    *(f32x4*)orow = o0;
    *(f32x4*)(orow + 4) = o1;
  }
}

extern "C" void kernel_launch(void* const* d_in, const int* in_sizes, int n_in,
                              void* d_out, int out_size, void* d_ws, size_t ws_size,
                              hipStream_t stream) {
  const float* X     = (const float*)d_in[0];
  const float* W     = (const float*)d_in[1];
  const float* degE  = (const float*)d_in[2];
  const float* degV  = (const float*)d_in[3];
  const float* Wdiag = (const float*)d_in[4];
  const int*   vidx  = (const int*)d_in[5];
  const int*   eidx  = (const int*)d_in[6];
  float* out = (float*)d_out;

  // workspace carve (all 256B aligned); total ~82 MB
  char* p = (char*)d_ws;
  auto take = [&](size_t bytes) { char* r = p; p += (bytes + 255) & ~(size_t)255; return r; };
  u16* Xb     = (u16*)take((size_t)MP * D * 2);   // bf16 X (rows >= NV unused garbage)
  u16* Wb     = (u16*)take((size_t)D * D * 2);    // bf16 W
  u16* Xp     = (u16*)take((size_t)MP * D * 2);   // bf16 projected features
  u16* Xe     = (u16*)take((size_t)NE * D * 2);   // bf16 edge features
  int* cntE   = (int*)take((size_t)NE * 4);
  int* offE   = (int*)take((size_t)NE * 4);
  int* curE   = (int*)take((size_t)NE * 4);
  int* cntV   = (int*)take((size_t)NV * 4);
  int* offV   = (int*)take((size_t)NV * 4);
  int* curV   = (int*)take((size_t)NV * 4);
  int* csr_ev = (int*)take((size_t)NNZp * 4);
  int* csr_ve = (int*)take((size_t)NNZp * 4);
  int* blkSum = (int*)take((size_t)(NBE + NBV) * 4);

  constexpr size_t NCONV = ((size_t)NV * D + (size_t)D * D) / 8 / 256;  // 12628 exact

  zero_kernel   <<<(NV + 255) / 256, 256, 0, stream>>>(cntE, cntV);
  hist_kernel   <<<(NNZp + 255) / 256, 256, 0, stream>>>(vidx, eidx, cntE, cntV);
  scan1_kernel  <<<NBE + NBV, 256, 0, stream>>>(cntE, cntV, offE, offV, blkSum);
  scan2_kernel  <<<1, 128, 0, stream>>>(blkSum);
  scan3_kernel  <<<NBE + NBV, 256, 0, stream>>>(offE, offV, curE, curV, blkSum);
  scatter_kernel<<<(NNZp + 255) / 256, 256, 0, stream>>>(vidx, eidx, curE, curV, csr_ev, csr_ve);
  convert_kernel<<<NCONV, 256, 0, stream>>>(X, W, Xb, Wb);
  gemm_kernel   <<<dim3(D / 128, MP / 128), 256, 0, stream>>>(Xb, Wb, Xp);
  stage1_kernel <<<SG1 * 16, 256, 0, stream>>>(Xp, offE, cntE, csr_ev, degE, Wdiag, Xe);
  stage2_kernel <<<SG2 * 8, 256, 0, stream>>>(Xe, offV, cntV, csr_ve, degV, out);
}

// Round 5
// 434.215 us; speedup vs baseline: 1.2411x; 1.0587x over previous
//
#include <hip/hip_runtime.h>

typedef unsigned short u16;
typedef unsigned int   u32;
typedef __attribute__((ext_vector_type(4))) float f32x4;
typedef __attribute__((ext_vector_type(4))) u32   u32x4;
typedef __attribute__((ext_vector_type(8))) __bf16 bf16x8;

constexpr int NV   = 50000;   // vertices
constexpr int NE   = 25000;   // hyperedges
constexpr int NNZp = 400000;  // incidence pairs
constexpr int D    = 512;     // d_in == d_out
constexpr int MP2  = 25088;   // NE padded to 128 (196*128) -- GEMM rows
constexpr int NBE  = 25;      // scan blocks for E (1024 elems each)
constexpr int NBV  = 49;      // scan blocks for V
constexpr int SG1  = 391;     // stage1 segment-groups: ceil(NE/64)
constexpr int SG2  = 1563;    // stage2 segment-groups: ceil(NV/32)

static __device__ __forceinline__ u16 f2bf(float f) {
  u32 u = __float_as_uint(f);
  u32 r = (u + 0x7fffu + ((u >> 16) & 1u)) >> 16;  // RNE
  return (u16)r;
}
static __device__ __forceinline__ u32 pk2(float a, float b) {
  return (u32)f2bf(a) | ((u32)f2bf(b) << 16);
}

static __device__ __forceinline__ void gload_lds16(const u16* g, u16* l) {
  // async global->LDS, 16B per lane; LDS dest = wave-uniform base + lane*16
  __builtin_amdgcn_global_load_lds(
      (const __attribute__((address_space(1))) u32*)g,
      (__attribute__((address_space(3))) u32*)l, 16, 0, 0);
}

// ---------------- zero segment counters ----------------
__global__ void zero_kernel(int* cntE, int* cntV) {
  int i = blockIdx.x * 256 + threadIdx.x;
  if (i < NE) cntE[i] = 0;
  if (i < NV) cntV[i] = 0;
}

// ---------------- histogram of incidence pairs ----------------
__global__ void hist_kernel(const int* __restrict__ vidx, const int* __restrict__ eidx,
                            int* cntE, int* cntV) {
  int i = blockIdx.x * 256 + threadIdx.x;
  if (i < NNZp) {
    atomicAdd(&cntE[eidx[i]], 1);
    atomicAdd(&cntV[vidx[i]], 1);
  }
}

// ---------------- scan pass 1: per-block (1024 elems) local exclusive scan -----------
__global__ __launch_bounds__(256) void scan1_kernel(
    const int* __restrict__ cntE, const int* __restrict__ cntV,
    int* offE, int* offV, int* blkSum) {
  const bool isE = blockIdx.x < NBE;
  const int* cnt = isE ? cntE : cntV;
  int* off = isE ? offE : offV;
  const int len = isE ? NE : NV;
  const int t = threadIdx.x;
  const int base = (isE ? blockIdx.x : blockIdx.x - NBE) * 1024 + t * 4;
  int4 c = {0, 0, 0, 0};
  if (base + 4 <= len) c = *(const int4*)(cnt + base);
  else {
    if (base + 0 < len) c.x = cnt[base + 0];
    if (base + 1 < len) c.y = cnt[base + 1];
    if (base + 2 < len) c.z = cnt[base + 2];
    if (base + 3 < len) c.w = cnt[base + 3];
  }
  int s = c.x + c.y + c.z + c.w;
  __shared__ int sm[256];
  sm[t] = s;
  __syncthreads();
  for (int d = 1; d < 256; d <<= 1) {
    int u = (t >= d) ? sm[t - d] : 0;
    __syncthreads();
    sm[t] += u;
    __syncthreads();
  }
  int ex = sm[t] - s;  // exclusive prefix within block
  int4 o;
  o.x = ex; o.y = o.x + c.x; o.z = o.y + c.y; o.w = o.z + c.z;
  if (base + 4 <= len) *(int4*)(off + base) = o;
  else {
    if (base + 0 < len) off[base + 0] = o.x;
    if (base + 1 < len) off[base + 1] = o.y;
    if (base + 2 < len) off[base + 2] = o.z;
    if (base + 3 < len) off[base + 3] = o.w;
  }
  if (t == 255) blkSum[blockIdx.x] = sm[255];
}

// ---------------- scan pass 2: wave-scan the 25+49 block sums (in-place, exclusive) --
__global__ void scan2_kernel(int* blkSum) {
  int wv = threadIdx.x >> 6, lane = threadIdx.x & 63;
  int off = wv ? NBE : 0, len = wv ? NBV : NBE;
  int v = (lane < len) ? blkSum[off + lane] : 0;
  int incl = v;
#pragma unroll
  for (int d = 1; d < 64; d <<= 1) {
    int u = __shfl_up(incl, d, 64);
    if (lane >= d) incl += u;
  }
  if (lane < len) blkSum[off + lane] = incl - v;
}

// ---------------- scan pass 3: add block prefixes, materialize off & cur -------------
__global__ __launch_bounds__(256) void scan3_kernel(
    int* offE, int* offV, int* curE, int* curV, const int* __restrict__ blkSum) {
  const bool isE = blockIdx.x < NBE;
  int* off = isE ? offE : offV;
  int* cur = isE ? curE : curV;
  const int len = isE ? NE : NV;
  const int pref = blkSum[blockIdx.x];
  const int base = (isE ? blockIdx.x : blockIdx.x - NBE) * 1024 + threadIdx.x * 4;
  if (base + 4 <= len) {
    int4 o = *(int4*)(off + base);
    o.x += pref; o.y += pref; o.z += pref; o.w += pref;
    *(int4*)(off + base) = o;
    *(int4*)(cur + base) = o;
  } else {
    for (int q = 0; q < 4; q++)
      if (base + q < len) { int v = off[base + q] + pref; off[base + q] = v; cur[base + q] = v; }
  }
}

// ---------------- scatter pairs into CSR ----------------
__global__ void scatter_kernel(const int* __restrict__ vidx, const int* __restrict__ eidx,
                               int* curE, int* curV, int* csr_ev, int* csr_ve) {
  int i = blockIdx.x * 256 + threadIdx.x;
  if (i < NNZp) {
    int e = eidx[i], v = vidx[i];
    csr_ev[atomicAdd(&curE[e], 1)] = v;  // edge -> member vertices
    csr_ve[atomicAdd(&curV[v], 1)] = e;  // vertex -> incident edges
  }
}

// ---------------- fp32 -> bf16 convert -----------------------------------------------
// X -> Xb in SLICE-MAJOR layout [16][NV][32] (each slice = contiguous 3.2 MB).
// W -> Wb row-major (GEMM B staging needs contiguous rows).
__global__ __launch_bounds__(256) void convert_kernel(
    const float* __restrict__ X, const float* __restrict__ W,
    u16* __restrict__ Xb, u16* __restrict__ Wb) {
  constexpr size_t NX = (size_t)NV * D;  // 25,600,000 (divisible by 8)
  size_t i = ((size_t)blockIdx.x * 256 + threadIdx.x) * 8;
  const float* src;
  u16* dst;
  if (i < NX) {
    int n = (int)(i >> 9);
    int col = (int)(i & 511);
    int t = col >> 5, w = col & 31;
    src = X + i;
    dst = Xb + (size_t)t * NV * 32 + (size_t)n * 32 + w;
  } else {
    src = W + (i - NX);
    dst = Wb + (i - NX);
  }
  f32x4 a = *(const f32x4*)src;
  f32x4 b = *(const f32x4*)(src + 4);
  u32x4 p = { pk2(a[0], a[1]), pk2(a[2], a[3]), pk2(b[0], b[1]), pk2(b[2], b[3]) };
  *(u32x4*)dst = p;
}

// ---------------- stage 1: vertex -> hyperedge on RAW Xb (aggregate-first) -----------
// 16 contiguous slices of 32 cols (3.2 MB each, fits one XCD L2); phase-major grid so
// each XCD streams ONE slice at a time. Wave = 16 groups x 4 lanes; each group owns one
// edge segment. Indices quad-prefetched via shfl. Output XeR row-major bf16 (unscaled).
__global__ __launch_bounds__(256) void stage1_kernel(
    const u16* __restrict__ Xb, const int* __restrict__ offE, const int* __restrict__ cntE,
    const int* __restrict__ csr_ev, u16* __restrict__ XeR) {
  const int wave = threadIdx.x >> 6;
  const int lane = threadIdx.x & 63;
  const int g    = lane >> 2;      // 0..15 group = segment
  const int c    = lane & 3;       // 4 lanes x 16B = 64B = 32 cols
  const int bid  = blockIdx.x;
  const int xcd  = bid & 7;
  const int tmp  = bid >> 3;                    // 0 .. 2*SG1-1
  const int phase = (tmp >= SG1) ? 1 : 0;
  const int sg    = tmp - phase * SG1;
  const int t     = xcd + 8 * phase;            // slice 0..15
  const int e     = sg * 64 + wave * 16 + g;
  const u16* base = Xb + (size_t)t * NV * 32;
  int start = 0, cnt = 0;
  if (e < NE) { start = offE[e]; cnt = cntE[e]; }
  float acc[8] = {};
  for (int j0 = 0; j0 < cnt; j0 += 4) {
    int idx = (j0 + c < cnt) ? csr_ev[start + j0 + c] : 0;
    int kmax = min(4, cnt - j0);
    for (int k = 0; k < kmax; k++) {
      int v = __shfl(idx, (lane & ~3) | k, 64);
      u32x4 p = *(const u32x4*)(base + (size_t)v * 32 + c * 8);
#pragma unroll
      for (int q = 0; q < 4; q++) {
        u32 u = p[q];
        acc[2 * q]     += __uint_as_float(u << 16);
        acc[2 * q + 1] += __uint_as_float(u & 0xffff0000u);
      }
    }
  }
  if (e < NE) {
    u32x4 o = { pk2(acc[0], acc[1]), pk2(acc[2], acc[3]),
                pk2(acc[4], acc[5]), pk2(acc[6], acc[7]) };
    *(u32x4*)(XeR + (size_t)e * D + t * 32 + c * 8) = o;
  }
}

// ---------------- GEMM: Xe2 = (XeR @ Wb^T) * (degE*Wdiag), slice-major output --------
// 128x128 tile, BK=32, 4 waves of 64x64, 16x16x32 MFMA (m97 structure). Only 25088
// rows (aggregate-first halves the GEMM vs projecting all 50048 vertices).
__global__ __launch_bounds__(256) void gemm_kernel(const u16* __restrict__ A,
                                                   const u16* __restrict__ B,
                                                   const float* __restrict__ degE,
                                                   const float* __restrict__ Wdiag,
                                                   u16* __restrict__ C) {
  __shared__ u16 sA[128 * 32];
  __shared__ u16 sB[128 * 32];
  const int tid  = threadIdx.x;
  const int lane = tid & 63;
  const int wave = tid >> 6;
  const int bm = blockIdx.y * 128;
  const int bn = blockIdx.x * 128;
  const int wm = (wave >> 1) * 64;
  const int wn = (wave & 1) * 64;
  const int lr = lane & 15;
  const int lk = (lane >> 4) * 8;
  const int srow = lane >> 2;        // 0..15: row within 16-row staging stripe
  const int scol = (lane & 3) * 8;   // 0/8/16/24: k-elem offset (16B)

  f32x4 acc[4][4] = {};

  for (int kt = 0; kt < D; kt += 32) {
    __syncthreads();  // previous iteration's LDS readers done
#pragma unroll
    for (int c = 0; c < 2; c++) {
      const int ar = wave * 16 + c * 64;          // wave-uniform stripe base row
      gload_lds16(A + (size_t)(bm + ar + srow) * D + kt + scol, &sA[ar * 32]);
      gload_lds16(B + (size_t)(bn + ar + srow) * D + kt + scol, &sB[ar * 32]);
    }
    __syncthreads();  // drains vmcnt: staging complete

    bf16x8 af[4], bfr[4];
#pragma unroll
    for (int i = 0; i < 4; i++) af[i]  = *(const bf16x8*)&sA[(wm + i * 16 + lr) * 32 + lk];
#pragma unroll
    for (int j = 0; j < 4; j++) bfr[j] = *(const bf16x8*)&sB[(wn + j * 16 + lr) * 32 + lk];
#pragma unroll
    for (int i = 0; i < 4; i++)
#pragma unroll
      for (int j = 0; j < 4; j++)
        acc[i][j] = __builtin_amdgcn_mfma_f32_16x16x32_bf16(af[i], bfr[j], acc[i][j], 0, 0, 0);
  }

  // C/D layout (16x16): col = lane&15, row = (lane>>4)*4 + reg
  // Output slice-major [8][MP2][64]; scale rows by degE*Wdiag.
#pragma unroll
  for (int i = 0; i < 4; i++)
#pragma unroll
    for (int r = 0; r < 4; r++) {
      int row = bm + wm + i * 16 + (lane >> 4) * 4 + r;
      if (row < NE) {
        float se = degE[row] * Wdiag[row];
#pragma unroll
        for (int j = 0; j < 4; j++) {
          int col = bn + wn + lr + j * 16;
          int s = col >> 6, w = col & 63;
          C[(size_t)s * MP2 * 64 + (size_t)row * 64 + w] = f2bf(acc[i][j][r] * se);
        }
      }
    }
}

// ---------------- stage 2: hyperedge -> vertex ---------------------------------------
// Xe2 slice-major [8][MP2][64]; slice = 3.21 MB contiguous, pinned via blockIdx&7.
// Wave = 8 groups x 8 lanes; each group owns one vertex; indices 8-prefetched.
__global__ __launch_bounds__(256) void stage2_kernel(
    const u16* __restrict__ Xe2, const int* __restrict__ offV, const int* __restrict__ cntV,
    const int* __restrict__ csr_ve, const float* __restrict__ degV, float* __restrict__ out) {
  const int wave = threadIdx.x >> 6;
  const int lane = threadIdx.x & 63;
  const int g    = lane >> 3;      // 0..7 group = segment
  const int c    = lane & 7;       // 8 lanes x 16B = 128B = 64 cols
  const int s    = blockIdx.x & 7;
  const int sg   = blockIdx.x >> 3;
  const int v    = sg * 32 + wave * 8 + g;
  const u16* base = Xe2 + (size_t)s * MP2 * 64;
  int start = 0, cnt = 0;
  if (v < NV) { start = offV[v]; cnt = cntV[v]; }
  float acc[8] = {};
  for (int j0 = 0; j0 < cnt; j0 += 8) {
    int idx = (j0 + c < cnt) ? csr_ve[start + j0 + c] : 0;
    int kmax = min(8, cnt - j0);
    for (int k = 0; k < kmax; k++) {
      int e = __shfl(idx, (lane & ~7) | k, 64);
      u32x4 p = *(const u32x4*)(base + (size_t)e * 64 + c * 8);
#pragma unroll
      for (int q = 0; q < 4; q++) {
        u32 u = p[q];
        acc[2 * q]     += __uint_as_float(u << 16);
        acc[2 * q + 1] += __uint_as_float(u & 0xffff0000u);
      }
    }
  }
  if (v < NV) {
    float sc = degV[v];
    float* orow = out + (size_t)v * D + s * 64 + c * 8;
    f32x4 o0 = { acc[0] * sc, acc[1] * sc, acc[2] * sc, acc[3] * sc };
    f32x4 o1 = { acc[4] * sc, acc[5] * sc, acc[6] * sc, acc[7] * sc };
    *(f32x4*)orow = o0;
    *(f32x4*)(orow + 4) = o1;
  }
}

extern "C" void kernel_launch(void* const* d_in, const int* in_sizes, int n_in,
                              void* d_out, int out_size, void* d_ws, size_t ws_size,
                              hipStream_t stream) {
  const float* X     = (const float*)d_in[0];
  const float* W     = (const float*)d_in[1];
  const float* degE  = (const float*)d_in[2];
  const float* degV  = (const float*)d_in[3];
  const float* Wdiag = (const float*)d_in[4];
  const int*   vidx  = (const int*)d_in[5];
  const int*   eidx  = (const int*)d_in[6];
  float* out = (float*)d_out;

  // workspace carve (all 256B aligned); total ~108 MB
  char* p = (char*)d_ws;
  auto take = [&](size_t bytes) { char* r = p; p += (bytes + 255) & ~(size_t)255; return r; };
  u16* Xb     = (u16*)take((size_t)NV * D * 2);    // bf16 X, slice-major [16][NV][32]
  u16* Wb     = (u16*)take((size_t)D * D * 2);     // bf16 W, row-major
  u16* XeR    = (u16*)take((size_t)MP2 * D * 2);   // bf16 raw edge sums, row-major
  u16* Xe2    = (u16*)take((size_t)MP2 * D * 2);   // bf16 projected+scaled, slice-major [8][MP2][64]
  int* cntE   = (int*)take((size_t)NE * 4);
  int* offE   = (int*)take((size_t)NE * 4);
  int* curE   = (int*)take((size_t)NE * 4);
  int* cntV   = (int*)take((size_t)NV * 4);
  int* offV   = (int*)take((size_t)NV * 4);
  int* curV   = (int*)take((size_t)NV * 4);
  int* csr_ev = (int*)take((size_t)NNZp * 4);
  int* csr_ve = (int*)take((size_t)NNZp * 4);
  int* blkSum = (int*)take((size_t)(NBE + NBV) * 4);

  constexpr size_t NCONV = ((size_t)NV * D + (size_t)D * D) / 8 / 256;  // 12628 exact

  zero_kernel   <<<(NV + 255) / 256, 256, 0, stream>>>(cntE, cntV);
  hist_kernel   <<<(NNZp + 255) / 256, 256, 0, stream>>>(vidx, eidx, cntE, cntV);
  scan1_kernel  <<<NBE + NBV, 256, 0, stream>>>(cntE, cntV, offE, offV, blkSum);
  scan2_kernel  <<<1, 128, 0, stream>>>(blkSum);
  scan3_kernel  <<<NBE + NBV, 256, 0, stream>>>(offE, offV, curE, curV, blkSum);
  scatter_kernel<<<(NNZp + 255) / 256, 256, 0, stream>>>(vidx, eidx, curE, curV, csr_ev, csr_ve);
  convert_kernel<<<NCONV, 256, 0, stream>>>(X, W, Xb, Wb);
  stage1_kernel <<<SG1 * 16, 256, 0, stream>>>(Xb, offE, cntE, csr_ev, XeR);
  gemm_kernel   <<<dim3(D / 128, MP2 / 128), 256, 0, stream>>>(XeR, Wb, degE, Wdiag, Xe2);
  stage2_kernel <<<SG2 * 8, 256, 0, stream>>>(Xe2, offV, cntV, csr_ve, degV, out);
}